// Round 9
// baseline (459.911 us; speedup 1.0000x reference)
//
#include <hip/hip_runtime.h>
#include <hip/hip_bf16.h>
#include <hip/hip_fp16.h>

// B=2 H=16 S=2048 DK=128, fp32 in/out. out = [context (B,H,S,DK) | attn (B,H,S,S)]
// R9 = R8 (gll-direct staging) with the vmcnt queue-order race fixed:
//   - sched_barrier(0) pins GLLs as oldest vmem ops each iteration
//   - LOADM unconditional (wrapped index) -> uniform vmcnt(4) accounting
//   - LGKM0 restored between P write and P readback
constexpr int Bc = 2, Hc = 16, Sc = 2048, Dc = 128;
constexpr int BQ = 64;   // q-rows per block (4 waves x 16)
constexpr int KT = 32;   // k-cols per iteration
constexpr int NT = Sc / KT;  // 64
constexpr int PSTRIDE = 40;  // halves per P-row
constexpr size_t SK = (size_t)Sc * Dc;
constexpr float SCALE = 0.08838834764831844f;  // 1/sqrt(128)

typedef _Float16 half8 __attribute__((ext_vector_type(8)));
typedef _Float16 half4v __attribute__((ext_vector_type(4)));
typedef float float4v __attribute__((ext_vector_type(4)));

#define SBAR() { __builtin_amdgcn_sched_barrier(0); \
                 __builtin_amdgcn_s_barrier(); \
                 __builtin_amdgcn_sched_barrier(0); }
#define LGKM0() { asm volatile("s_waitcnt lgkmcnt(0)" ::: "memory"); \
                  __builtin_amdgcn_sched_barrier(0); }
#define VMCNT(N) { asm volatile("s_waitcnt vmcnt(" #N ")" ::: "memory"); \
                   __builtin_amdgcn_sched_barrier(0); }
#define GLL16(G, L) __builtin_amdgcn_global_load_lds( \
    (const __attribute__((address_space(1))) void*)(G), \
    (__attribute__((address_space(3))) void*)(L), 16, 0, 0)

// ---------------- prep: fp32 -> fp16 copies of K and V ----------------
__global__ __launch_bounds__(256, 4)
void prep_kernel(const float* __restrict__ K, const float* __restrict__ V,
                 _Float16* __restrict__ Kh, _Float16* __restrict__ Vh)
{
    const int nb = gridDim.x >> 1;
    const bool isV = blockIdx.x >= nb;
    const float* src = isV ? V : K;
    _Float16* dst = isV ? Vh : Kh;
    const size_t base = ((size_t)(isV ? blockIdx.x - nb : blockIdx.x) * 256 + threadIdx.x) * 32;
    #pragma unroll
    for (int c = 0; c < 4; ++c) {
        float4v f0 = *(const float4v*)&src[base + c * 8];
        float4v f1 = *(const float4v*)&src[base + c * 8 + 4];
        half8 h8;
        #pragma unroll
        for (int i = 0; i < 4; ++i) { h8[i] = (_Float16)f0[i]; h8[4 + i] = (_Float16)f1[i]; }
        *(half8*)&dst[base + c * 8] = h8;
    }
}

// ---------------- main ----------------
__global__ __launch_bounds__(256, 3)
void sdpa_kernel(const float* __restrict__ Q, const _Float16* __restrict__ Kg,
                 const _Float16* __restrict__ Vg, const float* __restrict__ M,
                 float* __restrict__ outC, float* __restrict__ outA)
{
    __shared__ __align__(16) _Float16 Kl[2][KT * Dc];       // XOR-swizzled rows
    __shared__ __align__(16) _Float16 Vl[2][KT * Dc];       // tr-subtiled
    __shared__ __align__(16) _Float16 Pl[4][16 * PSTRIDE];  // per-wave P buf

    int bid = blockIdx.x;
    bid = (bid & 7) * 128 + (bid >> 3);   // XCD swizzle (1024 % 8 == 0)
    const int head = bid >> 5;
    const int q0   = (bid & 31) * BQ;

    const int tid  = threadIdx.x;
    const int wv   = tid >> 6;
    const int lane = tid & 63;
    const int g    = lane >> 4;
    const int c16  = lane & 15;
    const int qrow0 = q0 + wv * 16;

    const float*    Qh  = Q  + (size_t)head * SK;
    const _Float16* Khh = Kg + (size_t)head * SK;
    const _Float16* Vhh = Vg + (size_t)head * SK;
    const float*    Mh  = M  + (size_t)head * Sc * Sc;
    float* Ch = outC + (size_t)head * SK;
    float* Ah = outA + (size_t)head * Sc * Sc;

    // ---- Q A-fragments (fp16) ----
    half8 aq[4];
    {
        const float* qp = Qh + (size_t)(qrow0 + c16) * Dc + g * 8;
        #pragma unroll
        for (int c = 0; c < 4; ++c) {
            float4v f0 = *(const float4v*)(qp + c * 32);
            float4v f1 = *(const float4v*)(qp + c * 32 + 4);
            half8 h;
            #pragma unroll
            for (int j = 0; j < 4; ++j) { h[j] = (_Float16)f0[j]; h[4 + j] = (_Float16)f1[j]; }
            aq[c] = h;
        }
    }

    // ---- per-lane inverse-swizzled source offsets for global_load_lds ----
    // K: LDS granule g16 holds K[kr][woff ^ sw], kr=g16>>4, woff=(g16&15)*8, sw=(kr&7)*8
    int krK[2], offK[2], krV[2], offV[2];
    #pragma unroll
    for (int i = 0; i < 2; ++i) {
        const int gK = wv * 128 + i * 64 + lane;
        krK[i] = gK >> 4;
        offK[i] = ((gK & 15) * 8) ^ ((krK[i] & 7) * 8);
        // V: invert sub = ((t7*2 + (kq&1))*4 + (kq>>1)), base = sub*64 + (kr&3)*16
        const int gV = gK;
        const int sub = gV >> 3, gr = gV & 7, r2 = gr >> 1, oct = gr & 1;
        const int q_ = sub >> 2, s = sub & 3, t7 = q_ >> 1, kqL = q_ & 1;
        const int kq = s * 2 + kqL;
        krV[i] = kq * 4 + r2;
        offV[i] = t7 * 16 + oct * 8;
    }

    auto stage = [&](int t, int buf, bool withV) {
        #pragma unroll
        for (int i = 0; i < 2; ++i)
            GLL16(Khh + (size_t)(t * KT + krK[i]) * Dc + offK[i],
                  &Kl[buf][wv * 1024 + i * 512]);
        if (withV)
            #pragma unroll
            for (int i = 0; i < 2; ++i)
                GLL16(Vhh + (size_t)(t * KT + krV[i]) * Dc + offV[i],
                      &Vl[buf][wv * 1024 + i * 512]);
        __builtin_amdgcn_sched_barrier(0);   // pin GLLs as OLDEST vmem ops
    };

    auto qk = [&](int buf, float4v accS[2]) {
        #pragma unroll
        for (int sub = 0; sub < 2; ++sub) {
            const int krow = sub * 16 + c16;
            const _Float16* rp = &Kl[buf][krow * Dc];
            const int sw = (krow & 7) << 3;
            #pragma unroll
            for (int c = 0; c < 4; ++c) {
                half8 bk = *(const half8*)&rp[(c * 32 + g * 8) ^ sw];
                accS[sub] = __builtin_amdgcn_mfma_f32_16x16x32_f16(aq[c], bk, accS[sub], 0, 0, 0);
            }
        }
    };

    // ================= Pass A: row sums of exp(scores) =================
    float psum[4] = {0.f, 0.f, 0.f, 0.f};
    stage(0, 0, false);
    VMCNT(0); SBAR();
    for (int t = 0; t < NT; ++t) {
        const int cur = t & 1;
        if (t + 1 < NT) stage(t + 1, cur ^ 1, false);
        float4v accS[2] = {{0,0,0,0},{0,0,0,0}};
        qk(cur, accS);
        #pragma unroll
        for (int sub = 0; sub < 2; ++sub)
            #pragma unroll
            for (int r = 0; r < 4; ++r)
                psum[r] += __expf(accS[sub][r] * SCALE);
        VMCNT(0); SBAR();
    }

    #pragma unroll
    for (int m = 1; m < 16; m <<= 1)
        #pragma unroll
        for (int r = 0; r < 4; ++r)
            psum[r] += __shfl_xor(psum[r], m, 64);
    float invl[4];
    #pragma unroll
    for (int r = 0; r < 4; ++r) invl[r] = 1.0f / psum[r];

    // ================= Pass B =================
    float4v accC[8];
    #pragma unroll
    for (int d = 0; d < 8; ++d) accC[d] = (float4v){0, 0, 0, 0};

    float4v mA0, mA1, mB0, mB1;   // 2-deep M prefetch, named slots
    const float* mrow = Mh + (size_t)(qrow0 + c16) * Sc + g * 8;
#define LOADM(T, M0, M1) { const float* mp = mrow + (size_t)(T) * KT; \
    M0 = *(const float4v*)mp; M1 = *(const float4v*)(mp + 4); }

    // prologue: tile 0 into buf0 (GLLs pinned oldest), M 2-deep (4 loads newer)
    stage(0, 0, true);
    LOADM(0, mA0, mA1)
    LOADM(1, mB0, mB1)
    VMCNT(4); SBAR();

    const unsigned int vbase0 = (unsigned int)(uintptr_t)(&Vl[0][0]);
    _Float16* pw = &Pl[wv][0];

    half4v trA[4], trB[4];
#define TRI(D) { unsigned int a_ = vb + (D) * 1024 + lane * 8; \
    asm volatile("ds_read_b64_tr_b16 %0, %2\n\t" \
                 "ds_read_b64_tr_b16 %1, %2 offset:512" \
                 : "=&v"(trA[(D) & 3]), "=&v"(trB[(D) & 3]) : "v"(a_)); }
#define PVM(D, N) { \
    asm volatile("s_waitcnt lgkmcnt(" #N ")" ::: "memory"); \
    __builtin_amdgcn_sched_barrier(0); \
    half8 bv; \
    for (int j = 0; j < 4; ++j) { bv[j] = trA[(D) & 3][j]; bv[4 + j] = trB[(D) & 3][j]; } \
    accC[D] = __builtin_amdgcn_mfma_f32_16x16x32_f16(ap, bv, accC[D], 0, 0, 0); }

    // steady-state vmem queue at VMCNT(4), oldest->newest:
    //   [stores(T-1)x2, Mload(T+1)x2, GLLx4, stores(T)x2, Mload(T+2)x2]
    // wait<=4 drains through the GLLs, leaves [stores(T)x2, Mload(T+2)x2].
#define BODY(T, M0, M1) { \
    const int cur = (T) & 1; \
    if ((T) + 1 < NT) stage((T) + 1, cur ^ 1, true); \
    float4v accS[2] = {{0,0,0,0},{0,0,0,0}}; \
    qk(cur, accS); \
    _Pragma("unroll") \
    for (int sub = 0; sub < 2; ++sub) \
        _Pragma("unroll") \
        for (int r = 0; r < 4; ++r) { \
            float p = __expf(accS[sub][r] * SCALE) * invl[r]; \
            pw[(g * 4 + r) * PSTRIDE + sub * 16 + c16] = (_Float16)p; \
        } \
    LGKM0(); \
    half8 ph = *(const half8*)&pw[c16 * PSTRIDE + g * 8]; \
    float pf[8]; \
    _Pragma("unroll") \
    for (int j = 0; j < 8; ++j) pf[j] = (float)ph[j]; \
    float* as_ = &Ah[(size_t)(qrow0 + c16) * Sc + (T) * KT + g * 8]; \
    *(float4v*)as_       = (float4v){pf[0], pf[1], pf[2], pf[3]}; \
    *(float4v*)(as_ + 4) = (float4v){pf[4], pf[5], pf[6], pf[7]}; \
    half8 ap; \
    _Pragma("unroll") \
    for (int j = 0; j < 4; ++j) { \
        ap[j]     = (_Float16)(0.7f * pf[j]     + 0.3f * M0[j]); \
        ap[4 + j] = (_Float16)(0.7f * pf[4 + j] + 0.3f * M1[j]); \
    } \
    LOADM((((T) + 2) & (NT - 1)), M0, M1) \
    LGKM0(); \
    const unsigned int vb = vbase0 + (unsigned int)(cur * (KT * Dc * 2)); \
    TRI(0) TRI(1) \
    TRI(2) PVM(0, 4) \
    TRI(3) PVM(1, 4) \
    TRI(4) PVM(2, 4) \
    TRI(5) PVM(3, 4) \
    TRI(6) PVM(4, 4) \
    TRI(7) PVM(5, 4) \
    PVM(6, 2) \
    PVM(7, 0) \
    VMCNT(4); SBAR(); }

    for (int t = 0; t < NT; t += 2) {
        BODY(t,     mA0, mA1)
        BODY(t + 1, mB0, mB1)
    }

    // ================= epilogue: context =================
    #pragma unroll
    for (int d = 0; d < 8; ++d)
        #pragma unroll
        for (int r = 0; r < 4; ++r)
            Ch[(size_t)(qrow0 + g * 4 + r) * Dc + d * 16 + c16] = accC[d][r];
}

extern "C" void kernel_launch(void* const* d_in, const int* in_sizes, int n_in,
                              void* d_out, int out_size, void* d_ws, size_t ws_size,
                              hipStream_t stream) {
    const float* Q = (const float*)d_in[0];
    const float* K = (const float*)d_in[1];
    const float* V = (const float*)d_in[2];
    const float* M = (const float*)d_in[4];   // d_in[3] = attn_mask (unused)
    float* outC = (float*)d_out;
    float* outA = outC + (size_t)Bc * Hc * SK;

    _Float16* Kh = (_Float16*)d_ws;            // 16MB
    _Float16* Vh = Kh + (size_t)Bc * Hc * SK;  // +16MB

    // 2*B*H*S*D floats / (256 thr * 32 elem) = 2048 blocks
    prep_kernel<<<dim3(2048), dim3(256), 0, stream>>>(K, V, Kh, Vh);
    sdpa_kernel<<<dim3(1024), dim3(256), 0, stream>>>(Q, Kh, Vh, M, outC, outA);
}